// Round 7
// baseline (1087.329 us; speedup 1.0000x reference)
//
#include <hip/hip_runtime.h>

#define T_N   1024
#define B_N   64
#define CIN   32
#define COUT  32
#define MODES 16
#define DT    0.01f
#define PI_F  3.14159265358979323846f
#define W_SCALE 0.613592315154256f   /* 2*pi/(T_N*DT) */
#define W_NYQ  (-314.1592653589793f) /* -pi/DT */

// ---------------------------------------------------------------------------
// Radix-2 Stockham FFT, length 1024, LDS twiddle table.
// ---------------------------------------------------------------------------
template <int SIGN>
__device__ __forceinline__ void fft1024(float2* A, float2* B, const float2* TW, int tid) {
    float2* src = A;
    float2* dst = B;
    int m = 1;
#pragma unroll
    for (int s = 0; s < 10; ++s) {
        __syncthreads();
#pragma unroll
        for (int r = 0; r < 2; ++r) {
            int idx = tid + (r << 8);
            int k = idx & (m - 1);
            int j = idx >> s;
            float2 c0 = src[k + j * m];
            float2 c1 = src[k + j * m + 512];
            float2 w = TW[(j << s)];
            float ex = c0.x - c1.x, ey = c0.y - c1.y;
            dst[k + 2 * j * m]     = make_float2(c0.x + c1.x, c0.y + c1.y);
            dst[k + 2 * j * m + m] = make_float2(w.x * ex - w.y * ey, w.x * ey + w.y * ex);
        }
        float2* t = src; src = dst; dst = t;
        m <<= 1;
    }
    __syncthreads();
}

template <int SIGN>
__device__ __forceinline__ void build_tw(float2* TW, int tid) {
#pragma unroll
    for (int r = 0; r < 2; ++r) {
        int a = tid + (r << 8);
        float sn, cs;
        __sincosf((float)SIGN * PI_F * (float)a * (1.0f / 512.0f), &sn, &cs);
        TW[a] = make_float2(cs, sn);
    }
}

__global__ __launch_bounds__(256) void k_fft_fwd(const float* __restrict__ x,
                                                 float2* __restrict__ alpha) {
    __shared__ float2 A[1024];
    __shared__ float2 Bb[1024];
    __shared__ float2 TW[512];
    int row = blockIdx.x;
    int tid = threadIdx.x;
    build_tw<-1>(TW, tid);
    const float* xr = x + (size_t)row * T_N;
#pragma unroll
    for (int r = 0; r < 4; ++r) {
        int j = tid + (r << 8);
        A[j] = make_float2(xr[j], 0.0f);
    }
    fft1024<-1>(A, Bb, TW, tid);
    float2* outp = alpha + (size_t)row * T_N;
#pragma unroll
    for (int r = 0; r < 4; ++r) {
        int j = tid + (r << 8);
        outp[j] = A[j];
    }
}

// ---------------------------------------------------------------------------
// transpose alpha[(b*CIN+i)][x] -> alphaT[i][x][b]
// ---------------------------------------------------------------------------
__global__ __launch_bounds__(256) void k_transpose_a(const float2* __restrict__ alpha,
                                                     float2* __restrict__ alphaT) {
    __shared__ float2 T[32 * 66];
    int blk = blockIdx.x;
    int i = blk >> 5, xt = blk & 31;
    int tid = threadIdx.x;
#pragma unroll
    for (int r = 0; r < 8; ++r) {
        int e = tid + (r << 8);
        int xx = e & 31, b = e >> 5;
        T[xx * 66 + b] = alpha[((size_t)(b * CIN + i)) * T_N + xt * 32 + xx];
    }
    __syncthreads();
#pragma unroll
    for (int r = 0; r < 8; ++r) {
        int e = tid + (r << 8);
        int b = e & 63, xx = e >> 6;
        alphaT[((size_t)i * T_N + xt * 32 + xx) * B_N + b] = T[xx * 66 + b];
    }
}

// ---------------------------------------------------------------------------
// out1: per-frequency mixing (unchanged — works).
// ---------------------------------------------------------------------------
__global__ __launch_bounds__(256) void k_out1(const float4* __restrict__ alphaT4,
                                              const float* __restrict__ pr,
                                              const float* __restrict__ pim,
                                              const float* __restrict__ rr,
                                              const float* __restrict__ ri,
                                              float2* __restrict__ out1tmp) {
    __shared__ float sARe[32 * 64];
    __shared__ float sAIm[32 * 64];
    __shared__ float2 Hs[32 * 32];
    int x = blockIdx.x;
    int tid = threadIdx.x;

#pragma unroll
    for (int r = 0; r < 4; ++r) {
        int e = tid + (r << 8);
        int i = e >> 5, bp = e & 31;
        float4 v = alphaT4[((size_t)i * T_N + x) * (B_N / 2) + bp];
        *(float2*)&sARe[i * 64 + bp * 2] = make_float2(v.x, v.z);
        *(float2*)&sAIm[i * 64 + bp * 2] = make_float2(v.y, v.w);
    }

    int fx = x - ((x >= 512) ? 1024 : 0);
    float w = (float)fx * W_SCALE;
#pragma unroll
    for (int r = 0; r < 4; ++r) {
        int e = tid + (r << 8);
        int i = e >> 5, o = e & 31;
        int base = (i * COUT + o) * MODES;
        float hr = 0.f, hi = 0.f;
#pragma unroll
        for (int k = 0; k < MODES; ++k) {
            float a = pr[base + k], bI = pim[base + k];
            float d = w - bI;
            float inv = 1.0f / (a * a + d * d);
            float vR = -a * inv, vI = -d * inv;
            float sR = rr[base + k], sI = ri[base + k];
            hr += sR * vR - sI * vI;
            hi += sR * vI + sI * vR;
        }
        Hs[i * 32 + o] = make_float2(hr, hi);
    }
    __syncthreads();

    int o = tid & 31, bg = tid >> 5;
    float accR[8] = {}, accI[8] = {};
#pragma unroll 2
    for (int i = 0; i < CIN; ++i) {
        float2 h = Hs[i * 32 + o];
        float4 ar0 = *(const float4*)&sARe[i * 64 + bg * 8];
        float4 ar1 = *(const float4*)&sARe[i * 64 + bg * 8 + 4];
        float4 ai0 = *(const float4*)&sAIm[i * 64 + bg * 8];
        float4 ai1 = *(const float4*)&sAIm[i * 64 + bg * 8 + 4];
        float aR[8] = {ar0.x, ar0.y, ar0.z, ar0.w, ar1.x, ar1.y, ar1.z, ar1.w};
        float aI[8] = {ai0.x, ai0.y, ai0.z, ai0.w, ai1.x, ai1.y, ai1.z, ai1.w};
#pragma unroll
        for (int bb = 0; bb < 8; ++bb) {
            accR[bb] += aR[bb] * h.x - aI[bb] * h.y;
            accI[bb] += aR[bb] * h.y + aI[bb] * h.x;
        }
    }
#pragma unroll
    for (int bb = 0; bb < 8; ++bb) {
        out1tmp[(size_t)x * 2048 + (bg * 8 + bb) * 32 + o] =
            make_float2(accR[bb], accI[bb]);
    }
}

// ---------------------------------------------------------------------------
// out2 v7 (conjugate-folded, R3-style clean traffic):
// out2[b,o,k] = sum_i sum_{x=0..511} aR*C1 + aI*C2
// C1 = 2*p*r/(p^2+w^2), C2 = -2*w*r/(p^2+w^2) (minus folded in).
// x=0 col: aI slot carries Re(alpha[512]); C1 = r/p, C2 = -r/(i*w_nyq - p).
// Grid dim3(og:8, xh:2, i:32) = 512 blocks, 256 thr. Block owns 4 o's, 256 x,
// one i. Thread = 4b x 4k x 1o (32-float acc). chunk=(i,xh): 64 x 256KB = 16MB.
// Same-alpha-slice blocks have consecutive ids (og fastest) -> L2 sharing.
// ---------------------------------------------------------------------------
#define AROW4 36   /* f4 per alpha row: slot(bp)=(bp>>1)*2+(bp>>3)+(bp&1), max 34 */
#define VROW4 68   /* f4 per V row: slot(o',k)=o'*17+k, max 66 */
__global__ __launch_bounds__(256, 4) void k_out2(const float4* __restrict__ alphaT4,
                                                 const float* __restrict__ pr,
                                                 const float* __restrict__ pim,
                                                 const float* __restrict__ rr,
                                                 const float* __restrict__ ri,
                                                 float2* __restrict__ partial) {
    __shared__ __align__(16) float4 sA[8 * AROW4];   // 4.6 KB
    __shared__ __align__(16) float4 sV[8 * VROW4];   // 8.7 KB
    __shared__ float sPol[4][64];

    const int og = blockIdx.x, xh = blockIdx.y, i = blockIdx.z;
    const int tid = threadIdx.x;
    const int bg = tid & 15;            // 4 b's: b = bg*4+bi
    const int oq = (tid >> 4) & 3;      // o' within block
    const int kg = tid >> 6;            // 4 k's: k = kg*4+kk

    if (tid < 64) {
        int oo = tid >> 4, k = tid & 15;
        int pidx = (i * COUT + og * 4 + oo) * MODES + k;
        sPol[0][tid] = pr[pidx]; sPol[1][tid] = pim[pidx];
        sPol[2][tid] = rr[pidx]; sPol[3][tid] = ri[pidx];
    }
    __syncthreads();

    float accR[4][4] = {}, accI[4][4] = {};

    for (int t = 0; t < 32; ++t) {
        int x0 = xh * 256 + t * 8;
        __syncthreads();
        // stage alpha tile [8 xx][64 b] (256 f4, coalesced read, padded write)
        {
            int xx = tid >> 5, bp = tid & 31;
            float4 v = alphaT4[((size_t)i * T_N + x0 + xx) * 32 + bp];
            sA[xx * AROW4 + (bp >> 1) * 2 + (bp >> 3) + (bp & 1)] = v;
        }
        // V table: [8 xx][4 o'][16 k] f4 = (C1r,C1i,C2r,C2i)
#pragma unroll
        for (int r = 0; r < 2; ++r) {
            int e = tid + (r << 8);          // 0..511: xx=e>>6, rem=e&63
            int xx = e >> 6, rem = e & 63;
            int op = rem >> 4, k = rem & 15;
            int xg = x0 + xx;
            float a = sPol[0][rem], bI = sPol[1][rem];
            float sR = sPol[2][rem], sI = sPol[3][rem];
            float c1r, c1i, c2r, c2i;
            if (xg == 0) {
                float s1 = a * a + bI * bI;
                float q1r = a / s1, q1i = -bI / s1;
                c1r = sR * q1r - sI * q1i;
                c1i = sR * q1i + sI * q1r;
                float dr = -a, di = W_NYQ - bI;
                float s2 = dr * dr + di * di;
                float q2r = dr / s2, q2i = -di / s2;
                c2r = -(sR * q2r - sI * q2i);
                c2i = -(sR * q2i + sI * q2r);
            } else {
                float w = (float)xg * W_SCALE;
                float denr = a * a - bI * bI + w * w;
                float deni = 2.0f * a * bI;
                float s = denr * denr + deni * deni;
                float qr = denr / s, qi = -deni / s;
                float prr = a * sR - bI * sI;
                float pri = a * sI + bI * sR;
                c1r = 2.0f * (prr * qr - pri * qi);
                c1i = 2.0f * (prr * qi + pri * qr);
                float rqr = sR * qr - sI * qi;
                float rqi = sR * qi + sI * qr;
                c2r = -2.0f * w * rqr;
                c2i = -2.0f * w * rqi;
            }
            sV[xx * VROW4 + op * 17 + k] = make_float4(c1r, c1i, c2r, c2i);
        }
        __syncthreads();
        if (xh == 0 && t == 0) {
            // patch x=0 row: imag slots <- Re(alpha[b,i,512]) for all 64 b
            if (tid < 32) {
                float4 v = alphaT4[((size_t)i * T_N + 512) * 32 + tid];
                float* sAf = (float*)sA;
                int slot = (tid >> 1) * 2 + (tid >> 3) + (tid & 1);  // slot(bp=tid)
                sAf[slot * 4 + 1] = v.x;   // b = 2*tid
                sAf[slot * 4 + 3] = v.z;   // b = 2*tid+1
            }
            __syncthreads();
        }

        // MAC: 4b x 4k per thread per xx (6 b128 reads : 32 f4-FMA)
#pragma unroll
        for (int xx = 0; xx < 8; ++xx) {
            const float4 a0 = sA[xx * AROW4 + bg * 2 + (bg >> 2)];
            const float4 a1 = sA[xx * AROW4 + bg * 2 + (bg >> 2) + 1];
            const float4* vp = &sV[xx * VROW4 + oq * 17 + kg * 4];
            float4 v0 = vp[0], v1 = vp[1], v2 = vp[2], v3 = vp[3];
            float aR[4] = {a0.x, a0.z, a1.x, a1.z};
            float aI[4] = {a0.y, a0.w, a1.y, a1.w};
            float C1r[4] = {v0.x, v1.x, v2.x, v3.x};
            float C1i[4] = {v0.y, v1.y, v2.y, v3.y};
            float C2r[4] = {v0.z, v1.z, v2.z, v3.z};
            float C2i[4] = {v0.w, v1.w, v2.w, v3.w};
#pragma unroll
            for (int bi = 0; bi < 4; ++bi)
#pragma unroll
                for (int kk = 0; kk < 4; ++kk) {
                    accR[bi][kk] += aR[bi] * C1r[kk] + aI[bi] * C2r[kk];
                    accI[bi][kk] += aR[bi] * C1i[kk] + aI[bi] * C2i[kk];
                }
        }
    }

    // write partial chunk (i,xh): [b][o][k] float2, 32B contiguous per lane
    int chunk = i * 2 + xh;
    int o = og * 4 + oq;
    float2* dst = partial + (size_t)chunk * (B_N * COUT * MODES);
#pragma unroll
    for (int bi = 0; bi < 4; ++bi) {
        int b = bg * 4 + bi;
        int base = (b * COUT + o) * MODES + kg * 4;   // float2 index, even
        float4* p = (float4*)(dst + base);
        p[0] = make_float4(accR[bi][0], accI[bi][0], accR[bi][1], accI[bi][1]);
        p[1] = make_float4(accR[bi][2], accI[bi][2], accR[bi][3], accI[bi][3]);
    }
}

// ---------------------------------------------------------------------------
// reduce nchunk partials into o2[b][o][k]
// ---------------------------------------------------------------------------
__global__ __launch_bounds__(256) void k_reduce(const float4* __restrict__ p,
                                                float4* __restrict__ o2, int nchunk) {
    int f = blockIdx.x * 256 + threadIdx.x;   // 16384 float4s
    float4 s = make_float4(0.f, 0.f, 0.f, 0.f);
    for (int c = 0; c < nchunk; ++c) {
        float4 v = p[(size_t)c * 16384 + f];
        s.x += v.x; s.y += v.y; s.z += v.z; s.w += v.w;
    }
    o2[f] = s;
}

// ---------------------------------------------------------------------------
// transpose out1tmp[x][bo] -> out1T[bo][x]
// ---------------------------------------------------------------------------
__global__ __launch_bounds__(256) void k_transpose_o1(const float2* __restrict__ out1tmp,
                                                      float2* __restrict__ out1T) {
    __shared__ float2 T[64 * 33];
    int blk = blockIdx.x;
    int bot = blk >> 5, xt = blk & 31;
    int tid = threadIdx.x;
#pragma unroll
    for (int r = 0; r < 8; ++r) {
        int e = tid + (r << 8);
        int j = e & 63, xr = e >> 6;
        T[j * 33 + xr] = out1tmp[((size_t)(xt * 32 + xr)) * 2048 + bot * 64 + j];
    }
    __syncthreads();
#pragma unroll
    for (int r = 0; r < 8; ++r) {
        int e = tid + (r << 8);
        int xx = e & 31, j = e >> 5;
        out1T[((size_t)(bot * 64 + j)) * T_N + xt * 32 + xx] = T[j * 33 + xx];
    }
}

__global__ __launch_bounds__(256) void k_ifft(const float2* __restrict__ out1T,
                                              float* __restrict__ outp) {
    __shared__ float2 A[1024];
    __shared__ float2 Bb[1024];
    __shared__ float2 TW[512];
    int row = blockIdx.x;
    int tid = threadIdx.x;
    build_tw<1>(TW, tid);
    const float2* src = out1T + (size_t)row * T_N;
#pragma unroll
    for (int r = 0; r < 4; ++r) {
        int j = tid + (r << 8);
        A[j] = src[j];
    }
    fft1024<1>(A, Bb, TW, tid);
    float* dst = outp + (size_t)row * T_N;
    const float inv_n = 1.0f / (float)T_N;
#pragma unroll
    for (int r = 0; r < 4; ++r) {
        int j = tid + (r << 8);
        dst[j] = A[j].x * inv_n;
    }
}

// ---------------------------------------------------------------------------
// x2: grid dim3(cmh:4, zt:8, o:32), 256 thr. Thread 8b x 4z real acc.
// ---------------------------------------------------------------------------
#define PROW 100
#define EROW 132
__global__ __launch_bounds__(256, 4) void k_x2(const float4* __restrict__ o2f4,
                                               const float* __restrict__ pr,
                                               const float* __restrict__ pim,
                                               float* __restrict__ partial) {
    __shared__ __align__(16) float sPre[16 * PROW], sPim_[16 * PROW];
    __shared__ __align__(16) float sEre[16 * EROW], sEim[16 * EROW];
    __shared__ float s_pr[128], s_pim[128];

    const int cmh = blockIdx.x, zt = blockIdx.y, o = blockIdx.z;
    const int tid = threadIdx.x;
    const int zq = tid & 31, bq = tid >> 5;
    const int cmBase = cmh * 128;

    if (tid < 128) {
        int cm = cmBase + tid;
        int c = cm >> 4, m = cm & 15;
        int pidx = (c * COUT + o) * MODES + m;
        s_pr[tid] = pr[pidx];
        s_pim[tid] = pim[pidx];
    }

    float acc[8][4] = {};

    for (int t = 0; t < 8; ++t) {
        int cm0l = t * 16;
        __syncthreads();
#pragma unroll
        for (int r = 0; r < 2; ++r) {
            int e = tid + (r << 8);              // 0..511: b=e>>3, jp=e&7
            int b = e >> 3, jp = e & 7;
            float4 v = o2f4[b * 256 + ((cmBase + cm0l) >> 1) + jp];
            int j0 = jp * 2;
            int pa = (b >> 3) * 12 + (b & 7);
            sPre[j0 * PROW + pa] = v.x;
            sPim_[j0 * PROW + pa] = v.y;
            sPre[(j0 + 1) * PROW + pa] = v.z;
            sPim_[(j0 + 1) * PROW + pa] = v.w;
        }
#pragma unroll
        for (int r = 0; r < 8; ++r) {
            int e = tid + (r << 8);
            int z = e & 127, j = e >> 7;
            float gr = s_pr[cm0l + j], gi = s_pim[cm0l + j];
            float tz = (float)(zt * 128 + z) * DT;
            float er = __expf(gr * tz);
            float sn, cn;
            __sincosf(gi * tz, &sn, &cn);
            sEre[j * EROW + z] = er * cn;
            sEim[j * EROW + z] = er * sn;
        }
        __syncthreads();

#pragma unroll 4
        for (int j = 0; j < 16; ++j) {
            const float* pp = &sPre[j * PROW + bq * 12];
            const float* qq = &sPim_[j * PROW + bq * 12];
            float4 p0 = *(const float4*)&pp[0];
            float4 p1 = *(const float4*)&pp[4];
            float4 q0 = *(const float4*)&qq[0];
            float4 q1 = *(const float4*)&qq[4];
            float4 e0 = *(const float4*)&sEre[j * EROW + zq * 4];
            float4 e1 = *(const float4*)&sEim[j * EROW + zq * 4];
            float PRe[8] = {p0.x, p0.y, p0.z, p0.w, p1.x, p1.y, p1.z, p1.w};
            float PIm[8] = {q0.x, q0.y, q0.z, q0.w, q1.x, q1.y, q1.z, q1.w};
            float ERe[4] = {e0.x, e0.y, e0.z, e0.w};
            float EIm[4] = {e1.x, e1.y, e1.z, e1.w};
#pragma unroll
            for (int bb = 0; bb < 8; ++bb)
#pragma unroll
                for (int zz = 0; zz < 4; ++zz) {
                    acc[bb][zz] += PRe[bb] * ERe[zz] - PIm[bb] * EIm[zz];
                }
        }
    }

#pragma unroll
    for (int bb = 0; bb < 8; ++bb) {
        int b = bq * 8 + bb;
        size_t idx = (((size_t)cmh * B_N + b) * COUT + o) * T_N + zt * 128 + zq * 4;
        *(float4*)&partial[idx] = make_float4(acc[bb][0], acc[bb][1], acc[bb][2], acc[bb][3]);
    }
}

// ---------------------------------------------------------------------------
// x2 reduce: outp += (1/N) * sum_{cmh} partial
// ---------------------------------------------------------------------------
__global__ __launch_bounds__(256) void k_x2red(const float4* __restrict__ p,
                                               float4* __restrict__ outp) {
    int f = blockIdx.x * 256 + threadIdx.x;      // 0..524287 float4
    const float inv_n = 1.0f / (float)T_N;
    float4 s = make_float4(0.f, 0.f, 0.f, 0.f);
#pragma unroll
    for (int c = 0; c < 4; ++c) {
        float4 v = p[(size_t)c * 524288 + f];
        s.x += v.x; s.y += v.y; s.z += v.z; s.w += v.w;
    }
    float4 o = outp[f];
    o.x += s.x * inv_n; o.y += s.y * inv_n; o.z += s.z * inv_n; o.w += s.w * inv_n;
    outp[f] = o;
}

// ---------------------------------------------------------------------------
extern "C" void kernel_launch(void* const* d_in, const int* in_sizes, int n_in,
                              void* d_out, int out_size, void* d_ws, size_t ws_size,
                              hipStream_t stream) {
    const float* x   = (const float*)d_in[0];
    const float* pr  = (const float*)d_in[2];
    const float* pim = (const float*)d_in[3];
    const float* rr  = (const float*)d_in[4];
    const float* ri  = (const float*)d_in[5];
    float* outp = (float*)d_out;

    char* ws = (char*)d_ws;
    const size_t MB = 1024 * 1024;
    float2* alpha   = (float2*)ws;                     // [0,16M)
    float2* alphaT  = (float2*)(ws + 16 * MB);         // [16M,32M)
    float2* o2      = (float2*)(ws + 32 * MB);         // [32M,32.25M)
    float2* o2part  = (float2*)ws;                     // region A (alpha dead): 16MB
    float2* out1tmp = (float2*)ws;                     // region A (after reduce)
    float2* out1T   = (float2*)(ws + 16 * MB);         // region B (alphaT dead)
    float*  x2part  = (float*)ws;                      // [0,32M) (A+B dead)

    k_fft_fwd     <<<B_N * CIN, 256, 0, stream>>>(x, alpha);
    k_transpose_a <<<CIN * 32, 256, 0, stream>>>(alpha, alphaT);
    k_out2        <<<dim3(8, 2, 32), 256, 0, stream>>>((const float4*)alphaT,
                                                       pr, pim, rr, ri, o2part);
    k_reduce      <<<64, 256, 0, stream>>>((const float4*)o2part, (float4*)o2, 64);
    k_out1        <<<T_N, 256, 0, stream>>>((const float4*)alphaT,
                                            pr, pim, rr, ri, out1tmp);
    k_transpose_o1<<<32 * 32, 256, 0, stream>>>(out1tmp, out1T);
    k_ifft        <<<B_N * COUT, 256, 0, stream>>>(out1T, outp);
    k_x2          <<<dim3(4, 8, 32), 256, 0, stream>>>((const float4*)o2,
                                                       pr, pim, x2part);
    k_x2red       <<<2048, 256, 0, stream>>>((const float4*)x2part, (float4*)outp);
}

// Round 8
// 282.091 us; speedup vs baseline: 3.8545x; 3.8545x over previous
//
#include <hip/hip_runtime.h>

#define T_N   1024
#define B_N   64
#define CIN   32
#define COUT  32
#define MODES 16
#define DT    0.01f
#define PI_F  3.14159265358979323846f
#define W_SCALE 0.613592315154256f   /* 2*pi/(T_N*DT) */
#define W_NYQ  (-314.1592653589793f) /* -pi/DT */

// ---------------------------------------------------------------------------
// Radix-2 Stockham FFT, length 1024, LDS twiddle table.
// ---------------------------------------------------------------------------
template <int SIGN>
__device__ __forceinline__ void fft1024(float2* A, float2* B, const float2* TW, int tid) {
    float2* src = A;
    float2* dst = B;
    int m = 1;
#pragma unroll
    for (int s = 0; s < 10; ++s) {
        __syncthreads();
#pragma unroll
        for (int r = 0; r < 2; ++r) {
            int idx = tid + (r << 8);
            int k = idx & (m - 1);
            int j = idx >> s;
            float2 c0 = src[k + j * m];
            float2 c1 = src[k + j * m + 512];
            float2 w = TW[(j << s)];
            float ex = c0.x - c1.x, ey = c0.y - c1.y;
            dst[k + 2 * j * m]     = make_float2(c0.x + c1.x, c0.y + c1.y);
            dst[k + 2 * j * m + m] = make_float2(w.x * ex - w.y * ey, w.x * ey + w.y * ex);
        }
        float2* t = src; src = dst; dst = t;
        m <<= 1;
    }
    __syncthreads();
}

template <int SIGN>
__device__ __forceinline__ void build_tw(float2* TW, int tid) {
#pragma unroll
    for (int r = 0; r < 2; ++r) {
        int a = tid + (r << 8);
        float sn, cs;
        __sincosf((float)SIGN * PI_F * (float)a * (1.0f / 512.0f), &sn, &cs);
        TW[a] = make_float2(cs, sn);
    }
}

__global__ __launch_bounds__(256) void k_fft_fwd(const float* __restrict__ x,
                                                 float2* __restrict__ alpha) {
    __shared__ float2 A[1024];
    __shared__ float2 Bb[1024];
    __shared__ float2 TW[512];
    int row = blockIdx.x;
    int tid = threadIdx.x;
    build_tw<-1>(TW, tid);
    const float* xr = x + (size_t)row * T_N;
#pragma unroll
    for (int r = 0; r < 4; ++r) {
        int j = tid + (r << 8);
        A[j] = make_float2(xr[j], 0.0f);
    }
    fft1024<-1>(A, Bb, TW, tid);
    float2* outp = alpha + (size_t)row * T_N;
#pragma unroll
    for (int r = 0; r < 4; ++r) {
        int j = tid + (r << 8);
        outp[j] = A[j];
    }
}

// ---------------------------------------------------------------------------
// transpose alpha[(b*CIN+i)][x] -> alphaT[i][x][b]
// ---------------------------------------------------------------------------
__global__ __launch_bounds__(256) void k_transpose_a(const float2* __restrict__ alpha,
                                                     float2* __restrict__ alphaT) {
    __shared__ float2 T[32 * 66];
    int blk = blockIdx.x;
    int i = blk >> 5, xt = blk & 31;
    int tid = threadIdx.x;
#pragma unroll
    for (int r = 0; r < 8; ++r) {
        int e = tid + (r << 8);
        int xx = e & 31, b = e >> 5;
        T[xx * 66 + b] = alpha[((size_t)(b * CIN + i)) * T_N + xt * 32 + xx];
    }
    __syncthreads();
#pragma unroll
    for (int r = 0; r < 8; ++r) {
        int e = tid + (r << 8);
        int b = e & 63, xx = e >> 6;
        alphaT[((size_t)i * T_N + xt * 32 + xx) * B_N + b] = T[xx * 66 + b];
    }
}

// ---------------------------------------------------------------------------
// out1: per-frequency mixing (unchanged — works).
// ---------------------------------------------------------------------------
__global__ __launch_bounds__(256) void k_out1(const float4* __restrict__ alphaT4,
                                              const float* __restrict__ pr,
                                              const float* __restrict__ pim,
                                              const float* __restrict__ rr,
                                              const float* __restrict__ ri,
                                              float2* __restrict__ out1tmp) {
    __shared__ float sARe[32 * 64];
    __shared__ float sAIm[32 * 64];
    __shared__ float2 Hs[32 * 32];
    int x = blockIdx.x;
    int tid = threadIdx.x;

#pragma unroll
    for (int r = 0; r < 4; ++r) {
        int e = tid + (r << 8);
        int i = e >> 5, bp = e & 31;
        float4 v = alphaT4[((size_t)i * T_N + x) * (B_N / 2) + bp];
        *(float2*)&sARe[i * 64 + bp * 2] = make_float2(v.x, v.z);
        *(float2*)&sAIm[i * 64 + bp * 2] = make_float2(v.y, v.w);
    }

    int fx = x - ((x >= 512) ? 1024 : 0);
    float w = (float)fx * W_SCALE;
#pragma unroll
    for (int r = 0; r < 4; ++r) {
        int e = tid + (r << 8);
        int i = e >> 5, o = e & 31;
        int base = (i * COUT + o) * MODES;
        float hr = 0.f, hi = 0.f;
#pragma unroll
        for (int k = 0; k < MODES; ++k) {
            float a = pr[base + k], bI = pim[base + k];
            float d = w - bI;
            float inv = 1.0f / (a * a + d * d);
            float vR = -a * inv, vI = -d * inv;
            float sR = rr[base + k], sI = ri[base + k];
            hr += sR * vR - sI * vI;
            hi += sR * vI + sI * vR;
        }
        Hs[i * 32 + o] = make_float2(hr, hi);
    }
    __syncthreads();

    int o = tid & 31, bg = tid >> 5;
    float accR[8] = {}, accI[8] = {};
#pragma unroll 2
    for (int i = 0; i < CIN; ++i) {
        float2 h = Hs[i * 32 + o];
        float4 ar0 = *(const float4*)&sARe[i * 64 + bg * 8];
        float4 ar1 = *(const float4*)&sARe[i * 64 + bg * 8 + 4];
        float4 ai0 = *(const float4*)&sAIm[i * 64 + bg * 8];
        float4 ai1 = *(const float4*)&sAIm[i * 64 + bg * 8 + 4];
        float aR[8] = {ar0.x, ar0.y, ar0.z, ar0.w, ar1.x, ar1.y, ar1.z, ar1.w};
        float aI[8] = {ai0.x, ai0.y, ai0.z, ai0.w, ai1.x, ai1.y, ai1.z, ai1.w};
#pragma unroll
        for (int bb = 0; bb < 8; ++bb) {
            accR[bb] += aR[bb] * h.x - aI[bb] * h.y;
            accI[bb] += aR[bb] * h.y + aI[bb] * h.x;
        }
    }
#pragma unroll
    for (int bb = 0; bb < 8; ++bb) {
        out1tmp[(size_t)x * 2048 + (bg * 8 + bb) * 32 + o] =
            make_float2(accR[bb], accI[bb]);
    }
}

// ---------------------------------------------------------------------------
// out2 v8 = v7 structure, NO min-waves clamp (spill-free register allocation).
// out2[b,o,k] = sum_i sum_{x=0..511} aR*C1 + aI*C2
// C1 = 2*p*r/(p^2+w^2), C2 = -2*w*r/(p^2+w^2) (minus folded in).
// x=0 col: aI slot carries Re(alpha[512]); C1 = r/p, C2 = -r/(i*w_nyq - p).
// Grid dim3(og:8, xh:2, i:32) = 512 blocks, 256 thr. Thread = 4b x 4k x 1o.
// chunk=(i,xh): 64 x 256KB = 16MB. Same-slice blocks id-consecutive.
// ---------------------------------------------------------------------------
#define AROW4 36   /* f4 per alpha row: slot(bp)=bp+(bp>>3), max 34 */
#define VROW4 68   /* f4 per V row: slot(o',k)=o'*17+k, max 66 */
__global__ __launch_bounds__(256) void k_out2(const float4* __restrict__ alphaT4,
                                              const float* __restrict__ pr,
                                              const float* __restrict__ pim,
                                              const float* __restrict__ rr,
                                              const float* __restrict__ ri,
                                              float2* __restrict__ partial) {
    __shared__ __align__(16) float4 sA[8 * AROW4];   // 4.6 KB
    __shared__ __align__(16) float4 sV[8 * VROW4];   // 8.7 KB
    __shared__ float sPol[4][64];

    const int og = blockIdx.x, xh = blockIdx.y, i = blockIdx.z;
    const int tid = threadIdx.x;
    const int bg = tid & 15;            // 4 b's: b = bg*4+bi
    const int oq = (tid >> 4) & 3;      // o' within block
    const int kg = tid >> 6;            // 4 k's: k = kg*4+kk

    if (tid < 64) {
        int oo = tid >> 4, k = tid & 15;
        int pidx = (i * COUT + og * 4 + oo) * MODES + k;
        sPol[0][tid] = pr[pidx]; sPol[1][tid] = pim[pidx];
        sPol[2][tid] = rr[pidx]; sPol[3][tid] = ri[pidx];
    }
    __syncthreads();

    float accR[4][4] = {}, accI[4][4] = {};

    for (int t = 0; t < 32; ++t) {
        int x0 = xh * 256 + t * 8;
        __syncthreads();
        // stage alpha tile [8 xx][64 b] (256 f4, coalesced read, padded write)
        {
            int xx = tid >> 5, bp = tid & 31;
            float4 v = alphaT4[((size_t)i * T_N + x0 + xx) * 32 + bp];
            sA[xx * AROW4 + (bp >> 1) * 2 + (bp >> 3) + (bp & 1)] = v;
        }
        // V table: [8 xx][4 o'][16 k] f4 = (C1r,C1i,C2r,C2i)
#pragma unroll
        for (int r = 0; r < 2; ++r) {
            int e = tid + (r << 8);          // 0..511: xx=e>>6, rem=e&63
            int xx = e >> 6, rem = e & 63;
            int op = rem >> 4, k = rem & 15;
            int xg = x0 + xx;
            float a = sPol[0][rem], bI = sPol[1][rem];
            float sR = sPol[2][rem], sI = sPol[3][rem];
            float c1r, c1i, c2r, c2i;
            if (xg == 0) {
                float s1 = a * a + bI * bI;
                float q1r = a / s1, q1i = -bI / s1;
                c1r = sR * q1r - sI * q1i;
                c1i = sR * q1i + sI * q1r;
                float dr = -a, di = W_NYQ - bI;
                float s2 = dr * dr + di * di;
                float q2r = dr / s2, q2i = -di / s2;
                c2r = -(sR * q2r - sI * q2i);
                c2i = -(sR * q2i + sI * q2r);
            } else {
                float w = (float)xg * W_SCALE;
                float denr = a * a - bI * bI + w * w;
                float deni = 2.0f * a * bI;
                float s = denr * denr + deni * deni;
                float qr = denr / s, qi = -deni / s;
                float prr = a * sR - bI * sI;
                float pri = a * sI + bI * sR;
                c1r = 2.0f * (prr * qr - pri * qi);
                c1i = 2.0f * (prr * qi + pri * qr);
                float rqr = sR * qr - sI * qi;
                float rqi = sR * qi + sI * qr;
                c2r = -2.0f * w * rqr;
                c2i = -2.0f * w * rqi;
            }
            sV[xx * VROW4 + op * 17 + k] = make_float4(c1r, c1i, c2r, c2i);
        }
        __syncthreads();
        if (xh == 0 && t == 0) {
            // patch x=0 row: imag slots <- Re(alpha[b,i,512]) for all 64 b
            if (tid < 32) {
                float4 v = alphaT4[((size_t)i * T_N + 512) * 32 + tid];
                float* sAf = (float*)sA;
                int slot = (tid >> 1) * 2 + (tid >> 3) + (tid & 1);  // slot(bp=tid)
                sAf[slot * 4 + 1] = v.x;   // b = 2*tid
                sAf[slot * 4 + 3] = v.z;   // b = 2*tid+1
            }
            __syncthreads();
        }

        // MAC: 4b x 4k per thread per xx (6 b128 reads : 32 f4-FMA)
#pragma unroll
        for (int xx = 0; xx < 8; ++xx) {
            const float4 a0 = sA[xx * AROW4 + bg * 2 + (bg >> 2)];
            const float4 a1 = sA[xx * AROW4 + bg * 2 + (bg >> 2) + 1];
            const float4* vp = &sV[xx * VROW4 + oq * 17 + kg * 4];
            float4 v0 = vp[0], v1 = vp[1], v2 = vp[2], v3 = vp[3];
            float aR[4] = {a0.x, a0.z, a1.x, a1.z};
            float aI[4] = {a0.y, a0.w, a1.y, a1.w};
            float C1r[4] = {v0.x, v1.x, v2.x, v3.x};
            float C1i[4] = {v0.y, v1.y, v2.y, v3.y};
            float C2r[4] = {v0.z, v1.z, v2.z, v3.z};
            float C2i[4] = {v0.w, v1.w, v2.w, v3.w};
#pragma unroll
            for (int bi = 0; bi < 4; ++bi)
#pragma unroll
                for (int kk = 0; kk < 4; ++kk) {
                    accR[bi][kk] += aR[bi] * C1r[kk] + aI[bi] * C2r[kk];
                    accI[bi][kk] += aR[bi] * C1i[kk] + aI[bi] * C2i[kk];
                }
        }
    }

    // write partial chunk (i,xh): [b][o][k] float2, 32B contiguous per lane
    int chunk = i * 2 + xh;
    int o = og * 4 + oq;
    float2* dst = partial + (size_t)chunk * (B_N * COUT * MODES);
#pragma unroll
    for (int bi = 0; bi < 4; ++bi) {
        int b = bg * 4 + bi;
        int base = (b * COUT + o) * MODES + kg * 4;   // float2 index, even
        float4* p = (float4*)(dst + base);
        p[0] = make_float4(accR[bi][0], accI[bi][0], accR[bi][1], accI[bi][1]);
        p[1] = make_float4(accR[bi][2], accI[bi][2], accR[bi][3], accI[bi][3]);
    }
}

// ---------------------------------------------------------------------------
// reduce nchunk partials into o2[b][o][k]
// ---------------------------------------------------------------------------
__global__ __launch_bounds__(256) void k_reduce(const float4* __restrict__ p,
                                                float4* __restrict__ o2, int nchunk) {
    int f = blockIdx.x * 256 + threadIdx.x;   // 16384 float4s
    float4 s = make_float4(0.f, 0.f, 0.f, 0.f);
    for (int c = 0; c < nchunk; ++c) {
        float4 v = p[(size_t)c * 16384 + f];
        s.x += v.x; s.y += v.y; s.z += v.z; s.w += v.w;
    }
    o2[f] = s;
}

// ---------------------------------------------------------------------------
// transpose out1tmp[x][bo] -> out1T[bo][x]
// ---------------------------------------------------------------------------
__global__ __launch_bounds__(256) void k_transpose_o1(const float2* __restrict__ out1tmp,
                                                      float2* __restrict__ out1T) {
    __shared__ float2 T[64 * 33];
    int blk = blockIdx.x;
    int bot = blk >> 5, xt = blk & 31;
    int tid = threadIdx.x;
#pragma unroll
    for (int r = 0; r < 8; ++r) {
        int e = tid + (r << 8);
        int j = e & 63, xr = e >> 6;
        T[j * 33 + xr] = out1tmp[((size_t)(xt * 32 + xr)) * 2048 + bot * 64 + j];
    }
    __syncthreads();
#pragma unroll
    for (int r = 0; r < 8; ++r) {
        int e = tid + (r << 8);
        int xx = e & 31, j = e >> 5;
        out1T[((size_t)(bot * 64 + j)) * T_N + xt * 32 + xx] = T[j * 33 + xx];
    }
}

__global__ __launch_bounds__(256) void k_ifft(const float2* __restrict__ out1T,
                                              float* __restrict__ outp) {
    __shared__ float2 A[1024];
    __shared__ float2 Bb[1024];
    __shared__ float2 TW[512];
    int row = blockIdx.x;
    int tid = threadIdx.x;
    build_tw<1>(TW, tid);
    const float2* src = out1T + (size_t)row * T_N;
#pragma unroll
    for (int r = 0; r < 4; ++r) {
        int j = tid + (r << 8);
        A[j] = src[j];
    }
    fft1024<1>(A, Bb, TW, tid);
    float* dst = outp + (size_t)row * T_N;
    const float inv_n = 1.0f / (float)T_N;
#pragma unroll
    for (int r = 0; r < 4; ++r) {
        int j = tid + (r << 8);
        dst[j] = A[j].x * inv_n;
    }
}

// ---------------------------------------------------------------------------
// x2: grid dim3(cmh:4, zt:8, o:32), 256 thr. Thread 8b x 4z real acc.
// No min-waves clamp (avoid spills).
// ---------------------------------------------------------------------------
#define PROW 100
#define EROW 132
__global__ __launch_bounds__(256) void k_x2(const float4* __restrict__ o2f4,
                                            const float* __restrict__ pr,
                                            const float* __restrict__ pim,
                                            float* __restrict__ partial) {
    __shared__ __align__(16) float sPre[16 * PROW], sPim_[16 * PROW];
    __shared__ __align__(16) float sEre[16 * EROW], sEim[16 * EROW];
    __shared__ float s_pr[128], s_pim[128];

    const int cmh = blockIdx.x, zt = blockIdx.y, o = blockIdx.z;
    const int tid = threadIdx.x;
    const int zq = tid & 31, bq = tid >> 5;
    const int cmBase = cmh * 128;

    if (tid < 128) {
        int cm = cmBase + tid;
        int c = cm >> 4, m = cm & 15;
        int pidx = (c * COUT + o) * MODES + m;
        s_pr[tid] = pr[pidx];
        s_pim[tid] = pim[pidx];
    }

    float acc[8][4] = {};

    for (int t = 0; t < 8; ++t) {
        int cm0l = t * 16;
        __syncthreads();
#pragma unroll
        for (int r = 0; r < 2; ++r) {
            int e = tid + (r << 8);              // 0..511: b=e>>3, jp=e&7
            int b = e >> 3, jp = e & 7;
            float4 v = o2f4[b * 256 + ((cmBase + cm0l) >> 1) + jp];
            int j0 = jp * 2;
            int pa = (b >> 3) * 12 + (b & 7);
            sPre[j0 * PROW + pa] = v.x;
            sPim_[j0 * PROW + pa] = v.y;
            sPre[(j0 + 1) * PROW + pa] = v.z;
            sPim_[(j0 + 1) * PROW + pa] = v.w;
        }
#pragma unroll
        for (int r = 0; r < 8; ++r) {
            int e = tid + (r << 8);
            int z = e & 127, j = e >> 7;
            float gr = s_pr[cm0l + j], gi = s_pim[cm0l + j];
            float tz = (float)(zt * 128 + z) * DT;
            float er = __expf(gr * tz);
            float sn, cn;
            __sincosf(gi * tz, &sn, &cn);
            sEre[j * EROW + z] = er * cn;
            sEim[j * EROW + z] = er * sn;
        }
        __syncthreads();

#pragma unroll 4
        for (int j = 0; j < 16; ++j) {
            const float* pp = &sPre[j * PROW + bq * 12];
            const float* qq = &sPim_[j * PROW + bq * 12];
            float4 p0 = *(const float4*)&pp[0];
            float4 p1 = *(const float4*)&pp[4];
            float4 q0 = *(const float4*)&qq[0];
            float4 q1 = *(const float4*)&qq[4];
            float4 e0 = *(const float4*)&sEre[j * EROW + zq * 4];
            float4 e1 = *(const float4*)&sEim[j * EROW + zq * 4];
            float PRe[8] = {p0.x, p0.y, p0.z, p0.w, p1.x, p1.y, p1.z, p1.w};
            float PIm[8] = {q0.x, q0.y, q0.z, q0.w, q1.x, q1.y, q1.z, q1.w};
            float ERe[4] = {e0.x, e0.y, e0.z, e0.w};
            float EIm[4] = {e1.x, e1.y, e1.z, e1.w};
#pragma unroll
            for (int bb = 0; bb < 8; ++bb)
#pragma unroll
                for (int zz = 0; zz < 4; ++zz) {
                    acc[bb][zz] += PRe[bb] * ERe[zz] - PIm[bb] * EIm[zz];
                }
        }
    }

#pragma unroll
    for (int bb = 0; bb < 8; ++bb) {
        int b = bq * 8 + bb;
        size_t idx = (((size_t)cmh * B_N + b) * COUT + o) * T_N + zt * 128 + zq * 4;
        *(float4*)&partial[idx] = make_float4(acc[bb][0], acc[bb][1], acc[bb][2], acc[bb][3]);
    }
}

// ---------------------------------------------------------------------------
// x2 reduce: outp += (1/N) * sum_{cmh} partial
// ---------------------------------------------------------------------------
__global__ __launch_bounds__(256) void k_x2red(const float4* __restrict__ p,
                                               float4* __restrict__ outp) {
    int f = blockIdx.x * 256 + threadIdx.x;      // 0..524287 float4
    const float inv_n = 1.0f / (float)T_N;
    float4 s = make_float4(0.f, 0.f, 0.f, 0.f);
#pragma unroll
    for (int c = 0; c < 4; ++c) {
        float4 v = p[(size_t)c * 524288 + f];
        s.x += v.x; s.y += v.y; s.z += v.z; s.w += v.w;
    }
    float4 o = outp[f];
    o.x += s.x * inv_n; o.y += s.y * inv_n; o.z += s.z * inv_n; o.w += s.w * inv_n;
    outp[f] = o;
}

// ---------------------------------------------------------------------------
extern "C" void kernel_launch(void* const* d_in, const int* in_sizes, int n_in,
                              void* d_out, int out_size, void* d_ws, size_t ws_size,
                              hipStream_t stream) {
    const float* x   = (const float*)d_in[0];
    const float* pr  = (const float*)d_in[2];
    const float* pim = (const float*)d_in[3];
    const float* rr  = (const float*)d_in[4];
    const float* ri  = (const float*)d_in[5];
    float* outp = (float*)d_out;

    char* ws = (char*)d_ws;
    const size_t MB = 1024 * 1024;
    float2* alpha   = (float2*)ws;                     // [0,16M)
    float2* alphaT  = (float2*)(ws + 16 * MB);         // [16M,32M)
    float2* o2      = (float2*)(ws + 32 * MB);         // [32M,32.25M)
    float2* o2part  = (float2*)ws;                     // region A (alpha dead): 16MB
    float2* out1tmp = (float2*)ws;                     // region A (after reduce)
    float2* out1T   = (float2*)(ws + 16 * MB);         // region B (alphaT dead)
    float*  x2part  = (float*)ws;                      // [0,32M) (A+B dead)

    k_fft_fwd     <<<B_N * CIN, 256, 0, stream>>>(x, alpha);
    k_transpose_a <<<CIN * 32, 256, 0, stream>>>(alpha, alphaT);
    k_out2        <<<dim3(8, 2, 32), 256, 0, stream>>>((const float4*)alphaT,
                                                       pr, pim, rr, ri, o2part);
    k_reduce      <<<64, 256, 0, stream>>>((const float4*)o2part, (float4*)o2, 64);
    k_out1        <<<T_N, 256, 0, stream>>>((const float4*)alphaT,
                                            pr, pim, rr, ri, out1tmp);
    k_transpose_o1<<<32 * 32, 256, 0, stream>>>(out1tmp, out1T);
    k_ifft        <<<B_N * COUT, 256, 0, stream>>>(out1T, outp);
    k_x2          <<<dim3(4, 8, 32), 256, 0, stream>>>((const float4*)o2,
                                                       pr, pim, x2part);
    k_x2red       <<<2048, 256, 0, stream>>>((const float4*)x2part, (float4*)outp);
}